// Round 1
// baseline (410.799 us; speedup 1.0000x reference)
//
#include <hip/hip_runtime.h>
#include <stdint.h>

typedef __attribute__((ext_vector_type(8))) short short8;
typedef __attribute__((ext_vector_type(4))) float floatx4;

#define T_DIM 4096
#define D_DIM 128
#define BH_TOT 64
#define NCHUNK 8
#define CHUNK (T_DIM / NCHUNK) /* 512 */
#define LSTRIDE 72             /* u16 row stride: 144B, 16B-aligned, bank-uniform */

__device__ __forceinline__ unsigned short f2bf(float f) {
  unsigned int u = __float_as_uint(f);
  u = (u + 0x7FFFu + ((u >> 16) & 1u)) >> 16;  // RNE
  return (unsigned short)u;
}

__device__ __forceinline__ unsigned int pack2(float lo, float hi) {
  return (unsigned int)f2bf(lo) | ((unsigned int)f2bf(hi) << 16);
}

// ---------------- Phase 1: kvT[bh][e][d] = sum_t V[t][e] * K[t][d] ----------------
// A = V (m = e), B = K (n = d), k = t. Both staged transposed (t-contiguous) in LDS.
__global__ __launch_bounds__(256, 2)
void kv_phase1(const float* __restrict__ K, const float* __restrict__ V,
               float* __restrict__ kvT) {
  const int bh    = blockIdx.y;
  const int chunk = blockIdx.x;
  const int tid   = threadIdx.x;
  const int lane  = tid & 63;
  const int wv    = tid >> 6;      // wave 0..3
  const int c     = tid & 31;      // float4 column (4 d's)
  const int r     = tid >> 5;      // 0..7 (8-row group)
  const int m0    = (wv >> 1) * 64;  // e offset of wave tile
  const int n0    = (wv & 1) * 64;   // d offset of wave tile

  __shared__ unsigned short Vt[128 * LSTRIDE];
  __shared__ unsigned short Kt[128 * LSTRIDE];

  floatx4 acc[4][4];
#pragma unroll
  for (int i = 0; i < 4; ++i)
#pragma unroll
    for (int j = 0; j < 4; ++j) acc[i][j] = (floatx4){0.f, 0.f, 0.f, 0.f};

  const size_t base = ((size_t)bh * T_DIM + (size_t)chunk * CHUNK) * D_DIM;
  const float* Vp = V + base + 4 * c;
  const float* Kp = K + base + 4 * c;

  float4 ld[2][8];   // [op][t-sub-row], op0=V op1=K
  uint4  pk[2][4];   // packed bf16 columns: [op][j], 8 t-values each

  auto load_tile = [&](int tile) {
    const size_t roff = (size_t)(tile * 64 + 8 * r) * D_DIM;
#pragma unroll
    for (int i = 0; i < 8; ++i) {
      ld[0][i] = *(const float4*)(Vp + roff + (size_t)i * D_DIM);
      ld[1][i] = *(const float4*)(Kp + roff + (size_t)i * D_DIM);
    }
  };

  auto pack_all = [&]() {
#pragma unroll
    for (int op = 0; op < 2; ++op)
#pragma unroll
      for (int j = 0; j < 4; ++j) {
        uint4 v;
        v.x = (unsigned int)f2bf(((const float*)&ld[op][0])[j]) |
              ((unsigned int)f2bf(((const float*)&ld[op][1])[j]) << 16);
        v.y = (unsigned int)f2bf(((const float*)&ld[op][2])[j]) |
              ((unsigned int)f2bf(((const float*)&ld[op][3])[j]) << 16);
        v.z = (unsigned int)f2bf(((const float*)&ld[op][4])[j]) |
              ((unsigned int)f2bf(((const float*)&ld[op][5])[j]) << 16);
        v.w = (unsigned int)f2bf(((const float*)&ld[op][6])[j]) |
              ((unsigned int)f2bf(((const float*)&ld[op][7])[j]) << 16);
        pk[op][j] = v;
      }
  };

  load_tile(0);
  pack_all();

  for (int tile = 0; tile < CHUNK / 64; ++tile) {
    if (tile < CHUNK / 64 - 1) load_tile(tile + 1);  // prefetch overlaps pack/MFMA
    __syncthreads();  // previous MFMA fragment reads done
#pragma unroll
    for (int j = 0; j < 4; ++j) {
      *(uint4*)&Vt[(4 * c + j) * LSTRIDE + 8 * r] = pk[0][j];
      *(uint4*)&Kt[(4 * c + j) * LSTRIDE + 8 * r] = pk[1][j];
    }
    __syncthreads();

#pragma unroll
    for (int ks = 0; ks < 2; ++ks) {
      const int koff = 32 * ks + 8 * (lane >> 4);
      short8 af[4], bf[4];
#pragma unroll
      for (int tm = 0; tm < 4; ++tm)
        af[tm] = *(const short8*)&Vt[(m0 + tm * 16 + (lane & 15)) * LSTRIDE + koff];
#pragma unroll
      for (int tn = 0; tn < 4; ++tn)
        bf[tn] = *(const short8*)&Kt[(n0 + tn * 16 + (lane & 15)) * LSTRIDE + koff];
#pragma unroll
      for (int tm = 0; tm < 4; ++tm)
#pragma unroll
        for (int tn = 0; tn < 4; ++tn)
          acc[tm][tn] = __builtin_amdgcn_mfma_f32_16x16x32_bf16(af[tm], bf[tn],
                                                                acc[tm][tn], 0, 0, 0);
    }
    if (tile < CHUNK / 64 - 1) pack_all();  // waits on prefetch after MFMA issue
  }

  // C/D layout: col = lane&15 (n=d), row = (lane>>4)*4 + reg (m=e)
  float* dst = kvT + (size_t)bh * (128 * 128);
  const int col = lane & 15;
  const int rb  = (lane >> 4) * 4;
#pragma unroll
  for (int tm = 0; tm < 4; ++tm)
#pragma unroll
    for (int tn = 0; tn < 4; ++tn)
#pragma unroll
      for (int rg = 0; rg < 4; ++rg) {
        const int e = m0 + tm * 16 + rb + rg;
        const int d = n0 + tn * 16 + col;
        unsafeAtomicAdd(&dst[e * 128 + d], acc[tm][tn][rg]);
      }
}

// ---------------- Phase 2: out[t][e] = sum_d Q[t][d] * kvT[e][d] ----------------
// A = Q (m = t, k = d, row-major: no transpose). B[k=d][n=e] = kvT[e][d]: rows of ws
// are d-contiguous: no transpose. K=128 split into two 64-halves (LDS 36.9 KB).
__global__ __launch_bounds__(256, 2)
void qkv_phase2(const float* __restrict__ Q, const float* __restrict__ kvT,
                float* __restrict__ out) {
  const int bh   = blockIdx.y;
  const int t0   = blockIdx.x * 128;
  const int tid  = threadIdx.x;
  const int lane = tid & 63;
  const int wv   = tid >> 6;
  const int c    = tid & 15;   // float4 col within 64-wide half
  const int rq   = tid >> 4;   // 0..15 row group
  const int m0   = (wv >> 1) * 64;  // t offset of wave tile
  const int n0   = (wv & 1) * 64;   // e offset of wave tile

  __shared__ unsigned short Qs[128 * LSTRIDE];
  __shared__ unsigned short Bs[128 * LSTRIDE];

  const float* Qp = Q + ((size_t)bh * T_DIM + t0) * D_DIM;
  const float* Bp = kvT + (size_t)bh * (128 * 128);

  floatx4 acc[4][4];
#pragma unroll
  for (int i = 0; i < 4; ++i)
#pragma unroll
    for (int j = 0; j < 4; ++j) acc[i][j] = (floatx4){0.f, 0.f, 0.f, 0.f};

  for (int h = 0; h < 2; ++h) {
    float4 lq[8], lb[8];
    const int cb = h * 64 + 4 * c;
#pragma unroll
    for (int i = 0; i < 8; ++i) {
      const int row = rq + 16 * i;
      lq[i] = *(const float4*)(Qp + (size_t)row * D_DIM + cb);
      lb[i] = *(const float4*)(Bp + (size_t)row * 128 + cb);
    }
    __syncthreads();  // h=1: previous half's fragment reads done
#pragma unroll
    for (int i = 0; i < 8; ++i) {
      const int row = rq + 16 * i;
      uint2 q2, b2;
      q2.x = pack2(lq[i].x, lq[i].y);
      q2.y = pack2(lq[i].z, lq[i].w);
      b2.x = pack2(lb[i].x, lb[i].y);
      b2.y = pack2(lb[i].z, lb[i].w);
      *(uint2*)&Qs[row * LSTRIDE + 4 * c] = q2;
      *(uint2*)&Bs[row * LSTRIDE + 4 * c] = b2;
    }
    __syncthreads();

#pragma unroll
    for (int ks = 0; ks < 2; ++ks) {
      const int koff = 32 * ks + 8 * (lane >> 4);
      short8 af[4], bf[4];
#pragma unroll
      for (int tm = 0; tm < 4; ++tm)
        af[tm] = *(const short8*)&Qs[(m0 + tm * 16 + (lane & 15)) * LSTRIDE + koff];
#pragma unroll
      for (int tn = 0; tn < 4; ++tn)
        bf[tn] = *(const short8*)&Bs[(n0 + tn * 16 + (lane & 15)) * LSTRIDE + koff];
#pragma unroll
      for (int tm = 0; tm < 4; ++tm)
#pragma unroll
        for (int tn = 0; tn < 4; ++tn)
          acc[tm][tn] = __builtin_amdgcn_mfma_f32_16x16x32_bf16(af[tm], bf[tn],
                                                                acc[tm][tn], 0, 0, 0);
    }
  }

  float* op = out + ((size_t)bh * T_DIM + t0) * D_DIM;
  const int col = lane & 15;
  const int rb  = (lane >> 4) * 4;
#pragma unroll
  for (int tm = 0; tm < 4; ++tm)
#pragma unroll
    for (int tn = 0; tn < 4; ++tn)
#pragma unroll
      for (int rg = 0; rg < 4; ++rg)
        op[(size_t)(m0 + tm * 16 + rb + rg) * D_DIM + (n0 + tn * 16 + col)] =
            acc[tm][tn][rg];
}

extern "C" void kernel_launch(void* const* d_in, const int* in_sizes, int n_in,
                              void* d_out, int out_size, void* d_ws, size_t ws_size,
                              hipStream_t stream) {
  const float* Q = (const float*)d_in[0];
  const float* K = (const float*)d_in[1];
  const float* V = (const float*)d_in[2];
  float* out = (float*)d_out;
  float* kvT = (float*)d_ws;  // 64 * 128 * 128 fp32 = 4 MB

  hipMemsetAsync(d_ws, 0, (size_t)BH_TOT * 128 * 128 * sizeof(float), stream);
  kv_phase1<<<dim3(NCHUNK, BH_TOT), 256, 0, stream>>>(K, V, kvT);
  qkv_phase2<<<dim3(T_DIM / 128, BH_TOT), 256, 0, stream>>>(Q, kvT, out);
}